// Round 1
// baseline (2893.954 us; speedup 1.0000x reference)
//
#include <hip/hip_runtime.h>
#include <math.h>

// Problem constants
constexpr int NT = 4096;     // tokens
constexpr int H  = 1024;     // hidden
constexpr int V  = 50257;    // vocab
// cutoffs: [0, 20000, 40000, 50257]
constexpr int CUT1 = 20000;
constexpr int CUT2 = 40000;

constexpr int TILES0 = (20000 + 63) / 64;          // 313
constexpr int TILES1 = (20000 + 63) / 64;          // 313
constexpr int TILES2 = (V - 40000 + 63) / 64;      // 161
constexpr int TOTAL_CT = TILES0 + TILES1 + TILES2; // 787

// ---------------------------------------------------------------------------
// Kernel 1: single-block compaction — classify tokens by cluster, build perm.
// Also zero-initializes sumexp (ws is poisoned 0xAA before every launch).
// ---------------------------------------------------------------------------
__global__ __launch_bounds__(1024) void setup_kernel(
    const int* __restrict__ y, int* __restrict__ offsets,
    int* __restrict__ perm, float* __restrict__ sumexp) {
  __shared__ int cnt[3];
  __shared__ int base[3];
  int tid = threadIdx.x;
  if (tid < 3) cnt[tid] = 0;
  for (int i = tid; i < NT; i += 1024) sumexp[i] = 0.f;
  __syncthreads();

  int k[4];
  #pragma unroll
  for (int e = 0; e < 4; e++) {
    int t = tid + e * 1024;
    int v = y[t];
    int c = (v >= CUT1) + (v >= CUT2);
    k[e] = c;
    atomicAdd(&cnt[c], 1);
  }
  __syncthreads();
  if (tid == 0) {
    int o1 = cnt[0], o2 = cnt[0] + cnt[1];
    base[0] = 0; base[1] = o1; base[2] = o2;
    offsets[0] = 0; offsets[1] = o1; offsets[2] = o2; offsets[3] = NT;
    cnt[0] = 0; cnt[1] = 0; cnt[2] = 0;  // reuse as scatter cursors
  }
  __syncthreads();
  #pragma unroll
  for (int e = 0; e < 4; e++) {
    int t = tid + e * 1024;
    int pos = base[k[e]] + atomicAdd(&cnt[k[e]], 1);
    perm[pos] = t;
  }
}

// ---------------------------------------------------------------------------
// Kernel 2: per-token cluster-head log-softmax + target logit.
// One wave per token (4 tokens per 256-thread block).
// ---------------------------------------------------------------------------
__global__ __launch_bounds__(256) void head_kernel(
    const float* __restrict__ x, const int* __restrict__ y,
    const float* __restrict__ Wc, const float* __restrict__ logits,
    float* __restrict__ neg_cll, float* __restrict__ z_tgt) {
  int tid = threadIdx.x;
  int lane = tid & 63;
  int token = blockIdx.x * 4 + (tid >> 6);
  int yv = y[token];
  const float* xp = x + (size_t)token * H;
  float c0 = 0.f, c1 = 0.f, c2 = 0.f, zt = 0.f;
  #pragma unroll
  for (int j = 0; j < 16; j++) {
    int h = lane + j * 64;
    float xv = xp[h];
    c0 = fmaf(xv, Wc[h], c0);
    c1 = fmaf(xv, Wc[H + h], c1);
    c2 = fmaf(xv, Wc[2 * H + h], c2);
    zt = fmaf(xv, logits[(size_t)h * V + yv], zt);
  }
  #pragma unroll
  for (int d = 32; d; d >>= 1) {
    c0 += __shfl_down(c0, d);
    c1 += __shfl_down(c1, d);
    c2 += __shfl_down(c2, d);
    zt += __shfl_down(zt, d);
  }
  if (lane == 0) {
    float m = fmaxf(c0, fmaxf(c1, c2));
    float lse = m + logf(expf(c0 - m) + expf(c1 - m) + expf(c2 - m));
    int k = (yv >= CUT1) + (yv >= CUT2);
    float ck = (k == 0) ? c0 : ((k == 1) ? c1 : c2);
    neg_cll[token] = lse - ck;  // = -(c_k - lse)
    z_tgt[token] = zt;
  }
}

// ---------------------------------------------------------------------------
// Kernel 3: main tiled exp-sum GEMM. Block = 64 tokens x 64 cols, fp32.
// Each thread: 4x4 micro-tile; epilogue sums exp(z) over its cols, shuffle-
// reduces across the 16 threads of a token group, one atomicAdd per token.
// No max-subtraction needed (|z| <= 20.5 => exp-sum < 2e13, safe in fp32).
// ---------------------------------------------------------------------------
__global__ __launch_bounds__(256) void main_kernel(
    const float* __restrict__ x, const float* __restrict__ logits,
    const int* __restrict__ offsets, const int* __restrict__ perm,
    float* __restrict__ sumexp) {
  int ct = blockIdx.x;
  int c, lct;
  if (ct < TILES0)               { c = 0; lct = ct; }
  else if (ct < TILES0 + TILES1) { c = 1; lct = ct - TILES0; }
  else                           { c = 2; lct = ct - TILES0 - TILES1; }
  int colBase = (c == 0) ? 0 : ((c == 1) ? CUT1 : CUT2);
  int colEnd  = (c == 0) ? CUT1 : ((c == 1) ? CUT2 : V);
  int col0 = colBase + lct * 64;
  int ncols = min(64, colEnd - col0);

  int t0 = offsets[c] + blockIdx.y * 64;
  int tEnd = offsets[c + 1];
  if (t0 >= tEnd) return;
  int ntok = min(64, tEnd - t0);

  __shared__ int tok_s[64];
  __shared__ float xs[32][68];  // [k][token], pad 68: 4-way store conflict only
  __shared__ float ls[32][68];  // [k][col]

  int tid = threadIdx.x;
  if (tid < 64) tok_s[tid] = perm[t0 + min(tid, ntok - 1)];
  __syncthreads();

  int tg = tid >> 4;  // token group 0..15 -> tokens 4*tg..4*tg+3
  int cg = tid & 15;  // col group 0..15  -> cols  4*cg..4*cg+3
  float acc[4][4] = {};

  for (int h0 = 0; h0 < H; h0 += 32) {
    __syncthreads();
    // stage x chunk: 64 tokens x 32 k, coalesced 32-wide in k
    #pragma unroll
    for (int e = 0; e < 8; e++) {
      int elem = e * 256 + tid;
      int tt = elem >> 5, kk = elem & 31;
      xs[kk][tt] = x[(size_t)tok_s[tt] * H + h0 + kk];
    }
    // stage logits chunk: 32 k x 64 cols, coalesced 64-wide in col
    #pragma unroll
    for (int e = 0; e < 8; e++) {
      int elem = e * 256 + tid;
      int kk = elem >> 6, cc = elem & 63;
      ls[kk][cc] = (cc < ncols) ? logits[(size_t)(h0 + kk) * V + col0 + cc]
                                : 0.f;
    }
    __syncthreads();
    #pragma unroll
    for (int kk = 0; kk < 32; kk++) {
      float4 xv = *(const float4*)&xs[kk][4 * tg];
      float4 lv = *(const float4*)&ls[kk][4 * cg];
      acc[0][0] = fmaf(xv.x, lv.x, acc[0][0]);
      acc[0][1] = fmaf(xv.x, lv.y, acc[0][1]);
      acc[0][2] = fmaf(xv.x, lv.z, acc[0][2]);
      acc[0][3] = fmaf(xv.x, lv.w, acc[0][3]);
      acc[1][0] = fmaf(xv.y, lv.x, acc[1][0]);
      acc[1][1] = fmaf(xv.y, lv.y, acc[1][1]);
      acc[1][2] = fmaf(xv.y, lv.z, acc[1][2]);
      acc[1][3] = fmaf(xv.y, lv.w, acc[1][3]);
      acc[2][0] = fmaf(xv.z, lv.x, acc[2][0]);
      acc[2][1] = fmaf(xv.z, lv.y, acc[2][1]);
      acc[2][2] = fmaf(xv.z, lv.z, acc[2][2]);
      acc[2][3] = fmaf(xv.z, lv.w, acc[2][3]);
      acc[3][0] = fmaf(xv.w, lv.x, acc[3][0]);
      acc[3][1] = fmaf(xv.w, lv.y, acc[3][1]);
      acc[3][2] = fmaf(xv.w, lv.z, acc[3][2]);
      acc[3][3] = fmaf(xv.w, lv.w, acc[3][3]);
    }
  }

  // epilogue: per-token partial exp-sums over this thread's 4 cols
  float s[4];
  #pragma unroll
  for (int i = 0; i < 4; i++) {
    float v = 0.f;
    #pragma unroll
    for (int j = 0; j < 4; j++) {
      if (4 * cg + j < ncols) v += expf(acc[i][j]);
    }
    s[i] = v;
  }
  // reduce across the 16 col-group lanes (contiguous within a wave)
  #pragma unroll
  for (int i = 0; i < 4; i++) {
    #pragma unroll
    for (int d = 8; d; d >>= 1) s[i] += __shfl_down(s[i], d, 16);
  }
  if (cg == 0) {
    #pragma unroll
    for (int i = 0; i < 4; i++) {
      int tt = 4 * tg + i;
      if (tt < ntok) atomicAdd(&sumexp[tok_s[tt]], s[i]);
    }
  }
}

// ---------------------------------------------------------------------------
// Kernel 4: finalize. nll = neg_cll + log(sumexp) - z_target
// ---------------------------------------------------------------------------
__global__ __launch_bounds__(256) void final_kernel(
    const float* __restrict__ neg_cll, const float* __restrict__ z_tgt,
    const float* __restrict__ sumexp, float* __restrict__ out) {
  int i = blockIdx.x * 256 + threadIdx.x;
  if (i < NT) out[i] = neg_cll[i] + logf(sumexp[i]) - z_tgt[i];
}

extern "C" void kernel_launch(void* const* d_in, const int* in_sizes, int n_in,
                              void* d_out, int out_size, void* d_ws,
                              size_t ws_size, hipStream_t stream) {
  const float* x      = (const float*)d_in[0];
  const int*   y      = (const int*)d_in[1];
  const float* Wc     = (const float*)d_in[2];
  const float* logits = (const float*)d_in[3];
  float* out = (float*)d_out;

  char* ws = (char*)d_ws;
  int*   offsets = (int*)ws;                       // 4 ints
  int*   perm    = (int*)(ws + 16);                // 4096 ints
  float* neg_cll = (float*)(ws + 16 + NT * 4);     // 4096 f
  float* z_tgt   = neg_cll + NT;                   // 4096 f
  float* sumexp  = z_tgt + NT;                     // 4096 f

  setup_kernel<<<1, 1024, 0, stream>>>(y, offsets, perm, sumexp);
  head_kernel<<<NT / 4, 256, 0, stream>>>(x, y, Wc, logits, neg_cll, z_tgt);
  dim3 grid(TOTAL_CT, 64);
  main_kernel<<<grid, 256, 0, stream>>>(x, logits, offsets, perm, sumexp);
  final_kernel<<<NT / 256, 256, 0, stream>>>(neg_cll, z_tgt, sumexp, out);
}

// Round 2
// 752.174 us; speedup vs baseline: 3.8475x; 3.8475x over previous
//
#include <hip/hip_runtime.h>
#include <math.h>

typedef unsigned short ushort_t;
typedef __attribute__((ext_vector_type(8))) short short8;   // 8 bf16 = 4 VGPRs
typedef __attribute__((ext_vector_type(4))) float floatx4;  // MFMA accumulator

// Problem constants
constexpr int NT = 4096;     // tokens
constexpr int H  = 1024;     // hidden
constexpr int V  = 50257;    // vocab
constexpr int CUT1 = 20000;
constexpr int CUT2 = 40000;

// MFMA-path geometry
constexpr int NPAD_TOK = 4224;            // 4096 + 128 pad rows (zeroed)
constexpr int NPAD_COL = 50432;           // covers last col tile 50240..50367
constexpr int CT0 = 157, CT1 = 157, CT2 = 81;  // ceil(20000/128)x2, ceil(10257/128)
constexpr int CT_TOTAL = CT0 + CT1 + CT2;      // 395 col tiles
constexpr int MAX_TTILES = 32;                 // worst case: all tokens one cluster

// fp32 fallback geometry (round-1 path, used only if ws too small)
constexpr int FB_TILES0 = (20000 + 63) / 64;
constexpr int FB_TILES1 = (20000 + 63) / 64;
constexpr int FB_TILES2 = (V - 40000 + 63) / 64;
constexpr int FB_TOTAL = FB_TILES0 + FB_TILES1 + FB_TILES2;

__device__ __forceinline__ ushort_t f2bf(float f) {
  unsigned int u = __float_as_uint(f);
  u = (u + 0x7FFFu + ((u >> 16) & 1u)) >> 16;  // round-to-nearest-even
  return (ushort_t)u;
}
__device__ __forceinline__ float bf2f(ushort_t b) {
  return __uint_as_float(((unsigned int)b) << 16);
}
__device__ __forceinline__ void gl_lds16(const void* g, void* l) {
  __builtin_amdgcn_global_load_lds(
      (const __attribute__((address_space(1))) void*)g,
      (__attribute__((address_space(3))) void*)l, 16, 0, 0);
}

// ---------------------------------------------------------------------------
// Kernel 1: classify tokens by cluster, build perm, zero sumexp.
// ---------------------------------------------------------------------------
__global__ __launch_bounds__(1024) void setup_kernel(
    const int* __restrict__ y, int* __restrict__ offsets,
    int* __restrict__ perm, float* __restrict__ sumexp) {
  __shared__ int cnt[3];
  __shared__ int base[3];
  int tid = threadIdx.x;
  if (tid < 3) cnt[tid] = 0;
  for (int i = tid; i < NT; i += 1024) sumexp[i] = 0.f;
  __syncthreads();

  int k[4];
  #pragma unroll
  for (int e = 0; e < 4; e++) {
    int t = tid + e * 1024;
    int v = y[t];
    int c = (v >= CUT1) + (v >= CUT2);
    k[e] = c;
    atomicAdd(&cnt[c], 1);
  }
  __syncthreads();
  if (tid == 0) {
    int o1 = cnt[0], o2 = cnt[0] + cnt[1];
    base[0] = 0; base[1] = o1; base[2] = o2;
    offsets[0] = 0; offsets[1] = o1; offsets[2] = o2; offsets[3] = NT;
    cnt[0] = 0; cnt[1] = 0; cnt[2] = 0;
  }
  __syncthreads();
  #pragma unroll
  for (int e = 0; e < 4; e++) {
    int t = tid + e * 1024;
    int pos = base[k[e]] + atomicAdd(&cnt[k[e]], 1);
    perm[pos] = t;
  }
}

// ---------------------------------------------------------------------------
// Kernel 2: gather x into perm order as bf16; zero the pad rows.
// ---------------------------------------------------------------------------
__global__ __launch_bounds__(256) void gather_kernel(
    const float* __restrict__ x, const int* __restrict__ perm,
    ushort_t* __restrict__ xb) {
  int p = blockIdx.x;
  int src = (p < NT) ? perm[p] : -1;
  #pragma unroll
  for (int e = 0; e < 4; e++) {
    int k = e * 256 + threadIdx.x;
    float v = (src >= 0) ? x[(size_t)src * H + k] : 0.f;
    xb[(size_t)p * H + k] = (src >= 0) ? f2bf(v) : (ushort_t)0;
  }
}

// ---------------------------------------------------------------------------
// Kernel 3: transpose+convert logits [H][V] fp32 -> lt [NPAD_COL][H] bf16.
// 64x64 tiles through LDS; pad cols zero-filled.
// ---------------------------------------------------------------------------
__global__ __launch_bounds__(256) void transpose_kernel(
    const float* __restrict__ logits, ushort_t* __restrict__ lt) {
  __shared__ float ts[64][65];
  int col0 = blockIdx.x * 64, k0 = blockIdx.y * 64;
  int tid = threadIdx.x;
  #pragma unroll
  for (int e = 0; e < 16; e++) {
    int idx = e * 256 + tid;
    int r = idx >> 6, cc = idx & 63;
    int col = col0 + cc;
    ts[r][cc] = (col < V) ? logits[(size_t)(k0 + r) * V + col] : 0.f;
  }
  __syncthreads();
  #pragma unroll
  for (int e = 0; e < 16; e++) {
    int idx = e * 256 + tid;
    int kk = idx & 63, cc = idx >> 6;
    lt[(size_t)(col0 + cc) * H + k0 + kk] = f2bf(ts[kk][cc]);
  }
}

// ---------------------------------------------------------------------------
// Kernel 4: cluster-head log-softmax (fp32) + target logit (from bf16 lt,
// coalesced row read). One wave per token.
// ---------------------------------------------------------------------------
__global__ __launch_bounds__(256) void head_kernel(
    const float* __restrict__ x, const int* __restrict__ y,
    const float* __restrict__ Wc, const ushort_t* __restrict__ lt,
    float* __restrict__ neg_cll, float* __restrict__ z_tgt) {
  int tid = threadIdx.x;
  int lane = tid & 63;
  int token = blockIdx.x * 4 + (tid >> 6);
  int yv = y[token];
  const float* xp = x + (size_t)token * H;
  const ushort_t* lp = lt + (size_t)yv * H;
  float c0 = 0.f, c1 = 0.f, c2 = 0.f, zt = 0.f;
  #pragma unroll
  for (int j = 0; j < 16; j++) {
    int h = lane + j * 64;
    float xv = xp[h];
    c0 = fmaf(xv, Wc[h], c0);
    c1 = fmaf(xv, Wc[H + h], c1);
    c2 = fmaf(xv, Wc[2 * H + h], c2);
    zt = fmaf(xv, bf2f(lp[h]), zt);
  }
  #pragma unroll
  for (int d = 32; d; d >>= 1) {
    c0 += __shfl_down(c0, d);
    c1 += __shfl_down(c1, d);
    c2 += __shfl_down(c2, d);
    zt += __shfl_down(zt, d);
  }
  if (lane == 0) {
    float m = fmaxf(c0, fmaxf(c1, c2));
    float lse = m + logf(expf(c0 - m) + expf(c1 - m) + expf(c2 - m));
    int k = (yv >= CUT1) + (yv >= CUT2);
    float ck = (k == 0) ? c0 : ((k == 1) ? c1 : c2);
    neg_cll[token] = lse - ck;
    z_tgt[token] = zt;
  }
}

// ---------------------------------------------------------------------------
// Kernel 5: MFMA main loop. Block = 128 tokens x 128 cols, 4 waves in 2x2,
// BK=32, global_load_lds width-16 staging, fused exp-sum epilogue into
// sumexp_perm (perm-order token index).
// ---------------------------------------------------------------------------
__global__ __launch_bounds__(256) void mfma_kernel(
    const ushort_t* __restrict__ xb, const ushort_t* __restrict__ lt,
    const int* __restrict__ offsets, float* __restrict__ sumexp) {
  int ct = blockIdx.x;
  int c, col0, colEnd;
  if (ct < CT0)            { c = 0; col0 = ct * 128;                    colEnd = CUT1; }
  else if (ct < CT0 + CT1) { c = 1; col0 = CUT1 + (ct - CT0) * 128;     colEnd = CUT2; }
  else                     { c = 2; col0 = CUT2 + (ct - CT0 - CT1) * 128; colEnd = V; }

  int t0 = offsets[c] + blockIdx.y * 128;
  int tEnd = offsets[c + 1];
  if (t0 >= tEnd) return;

  __shared__ __align__(16) ushort_t xs[128 * 32];  // [token][k] 64B rows
  __shared__ __align__(16) ushort_t ls[128 * 32];  // [col][k]   64B rows

  int tid = threadIdx.x;
  int lane = tid & 63;
  int w = tid >> 6;                 // wave 0..3
  int wm = w >> 1, wn = w & 1;      // 2x2 wave grid
  int m_in = lane & 15, quad = lane >> 4;

  // staging: wave w stages rows [w*32, w*32+32) of each tile;
  // lane covers row srow (16B chunk schunk) of a 16-row group.
  int srow = lane >> 2;
  int schunk = (lane & 3) * 8;
  const ushort_t* ga0 = xb + (size_t)(t0 + w * 32 + srow) * H + schunk;
  const ushort_t* ga1 = ga0 + (size_t)16 * H;
  const ushort_t* gb0 = lt + (size_t)(col0 + w * 32 + srow) * H + schunk;
  const ushort_t* gb1 = gb0 + (size_t)16 * H;
  ushort_t* la0 = &xs[(w * 32) * 32];
  ushort_t* la1 = &xs[(w * 32 + 16) * 32];
  ushort_t* lb0 = &ls[(w * 32) * 32];
  ushort_t* lb1 = &ls[(w * 32 + 16) * 32];

  floatx4 acc[4][4];
  #pragma unroll
  for (int i = 0; i < 4; i++)
    #pragma unroll
    for (int j = 0; j < 4; j++)
      acc[i][j] = (floatx4){0.f, 0.f, 0.f, 0.f};

  for (int k0 = 0; k0 < H; k0 += 32) {
    __syncthreads();
    gl_lds16(ga0, la0);
    gl_lds16(ga1, la1);
    gl_lds16(gb0, lb0);
    gl_lds16(gb1, lb1);
    ga0 += 32; ga1 += 32; gb0 += 32; gb1 += 32;
    __syncthreads();

    short8 af[4], bf[4];
    #pragma unroll
    for (int i = 0; i < 4; i++)
      af[i] = *(const short8*)&xs[(wm * 64 + i * 16 + m_in) * 32 + quad * 8];
    #pragma unroll
    for (int j = 0; j < 4; j++)
      bf[j] = *(const short8*)&ls[(wn * 64 + j * 16 + m_in) * 32 + quad * 8];
    #pragma unroll
    for (int i = 0; i < 4; i++)
      #pragma unroll
      for (int j = 0; j < 4; j++)
        acc[i][j] = __builtin_amdgcn_mfma_f32_16x16x32_bf16(af[i], bf[j], acc[i][j], 0, 0, 0);
  }

  // Epilogue: C/D layout col=lane&15, row=quad*4+reg (verified m89/m91).
  #pragma unroll
  for (int i = 0; i < 4; i++) {
    #pragma unroll
    for (int r = 0; r < 4; r++) {
      float s = 0.f;
      #pragma unroll
      for (int j = 0; j < 4; j++) {
        int col = col0 + wn * 64 + j * 16 + m_in;
        if (col < colEnd) s += __expf(acc[i][j][r]);
      }
      s += __shfl_down(s, 8, 16);
      s += __shfl_down(s, 4, 16);
      s += __shfl_down(s, 2, 16);
      s += __shfl_down(s, 1, 16);
      if (m_in == 0) {
        int rowt = wm * 64 + i * 16 + quad * 4 + r;
        if (t0 + rowt < tEnd) atomicAdd(&sumexp[t0 + rowt], s);
      }
    }
  }
}

// ---------------------------------------------------------------------------
// Kernel 6: finalize. sumexp is perm-indexed; scatter to token order.
// ---------------------------------------------------------------------------
__global__ __launch_bounds__(256) void final_kernel(
    const int* __restrict__ perm, const float* __restrict__ neg_cll,
    const float* __restrict__ z_tgt, const float* __restrict__ sumexp,
    float* __restrict__ out) {
  int p = blockIdx.x * 256 + threadIdx.x;
  if (p < NT) {
    int t = perm[p];
    out[t] = neg_cll[t] + logf(sumexp[p]) - z_tgt[t];
  }
}

// ===========================================================================
// Round-1 fp32 fallback path (used only if ws_size is too small for lt/xb).
// ===========================================================================
__global__ __launch_bounds__(256) void head_kernel_fb(
    const float* __restrict__ x, const int* __restrict__ y,
    const float* __restrict__ Wc, const float* __restrict__ logits,
    float* __restrict__ neg_cll, float* __restrict__ z_tgt) {
  int tid = threadIdx.x;
  int lane = tid & 63;
  int token = blockIdx.x * 4 + (tid >> 6);
  int yv = y[token];
  const float* xp = x + (size_t)token * H;
  float c0 = 0.f, c1 = 0.f, c2 = 0.f, zt = 0.f;
  #pragma unroll
  for (int j = 0; j < 16; j++) {
    int h = lane + j * 64;
    float xv = xp[h];
    c0 = fmaf(xv, Wc[h], c0);
    c1 = fmaf(xv, Wc[H + h], c1);
    c2 = fmaf(xv, Wc[2 * H + h], c2);
    zt = fmaf(xv, logits[(size_t)h * V + yv], zt);
  }
  #pragma unroll
  for (int d = 32; d; d >>= 1) {
    c0 += __shfl_down(c0, d);
    c1 += __shfl_down(c1, d);
    c2 += __shfl_down(c2, d);
    zt += __shfl_down(zt, d);
  }
  if (lane == 0) {
    float m = fmaxf(c0, fmaxf(c1, c2));
    float lse = m + logf(expf(c0 - m) + expf(c1 - m) + expf(c2 - m));
    int k = (yv >= CUT1) + (yv >= CUT2);
    float ck = (k == 0) ? c0 : ((k == 1) ? c1 : c2);
    neg_cll[token] = lse - ck;
    z_tgt[token] = zt;
  }
}

__global__ __launch_bounds__(256) void main_kernel_fb(
    const float* __restrict__ x, const float* __restrict__ logits,
    const int* __restrict__ offsets, const int* __restrict__ perm,
    float* __restrict__ sumexp) {
  int ct = blockIdx.x;
  int c, lct;
  if (ct < FB_TILES0)                  { c = 0; lct = ct; }
  else if (ct < FB_TILES0 + FB_TILES1) { c = 1; lct = ct - FB_TILES0; }
  else                                 { c = 2; lct = ct - FB_TILES0 - FB_TILES1; }
  int colBase = (c == 0) ? 0 : ((c == 1) ? CUT1 : CUT2);
  int colEnd  = (c == 0) ? CUT1 : ((c == 1) ? CUT2 : V);
  int col0 = colBase + lct * 64;
  int ncols = min(64, colEnd - col0);

  int t0 = offsets[c] + blockIdx.y * 64;
  int tEnd = offsets[c + 1];
  if (t0 >= tEnd) return;
  int ntok = min(64, tEnd - t0);

  __shared__ int tok_s[64];
  __shared__ float xs[32][68];
  __shared__ float lsm[32][68];

  int tid = threadIdx.x;
  if (tid < 64) tok_s[tid] = perm[t0 + min(tid, ntok - 1)];
  __syncthreads();

  int tg = tid >> 4;
  int cg = tid & 15;
  float acc[4][4] = {};

  for (int h0 = 0; h0 < H; h0 += 32) {
    __syncthreads();
    #pragma unroll
    for (int e = 0; e < 8; e++) {
      int elem = e * 256 + tid;
      int tt = elem >> 5, kk = elem & 31;
      xs[kk][tt] = x[(size_t)tok_s[tt] * H + h0 + kk];
    }
    #pragma unroll
    for (int e = 0; e < 8; e++) {
      int elem = e * 256 + tid;
      int kk = elem >> 6, cc = elem & 63;
      lsm[kk][cc] = (cc < ncols) ? logits[(size_t)(h0 + kk) * V + col0 + cc] : 0.f;
    }
    __syncthreads();
    #pragma unroll
    for (int kk = 0; kk < 32; kk++) {
      float4 xv = *(const float4*)&xs[kk][4 * tg];
      float4 lv = *(const float4*)&lsm[kk][4 * cg];
      acc[0][0] = fmaf(xv.x, lv.x, acc[0][0]);
      acc[0][1] = fmaf(xv.x, lv.y, acc[0][1]);
      acc[0][2] = fmaf(xv.x, lv.z, acc[0][2]);
      acc[0][3] = fmaf(xv.x, lv.w, acc[0][3]);
      acc[1][0] = fmaf(xv.y, lv.x, acc[1][0]);
      acc[1][1] = fmaf(xv.y, lv.y, acc[1][1]);
      acc[1][2] = fmaf(xv.y, lv.z, acc[1][2]);
      acc[1][3] = fmaf(xv.y, lv.w, acc[1][3]);
      acc[2][0] = fmaf(xv.z, lv.x, acc[2][0]);
      acc[2][1] = fmaf(xv.z, lv.y, acc[2][1]);
      acc[2][2] = fmaf(xv.z, lv.z, acc[2][2]);
      acc[2][3] = fmaf(xv.z, lv.w, acc[2][3]);
      acc[3][0] = fmaf(xv.w, lv.x, acc[3][0]);
      acc[3][1] = fmaf(xv.w, lv.y, acc[3][1]);
      acc[3][2] = fmaf(xv.w, lv.z, acc[3][2]);
      acc[3][3] = fmaf(xv.w, lv.w, acc[3][3]);
    }
  }

  float s[4];
  #pragma unroll
  for (int i = 0; i < 4; i++) {
    float v = 0.f;
    #pragma unroll
    for (int j = 0; j < 4; j++) {
      if (4 * cg + j < ncols) v += expf(acc[i][j]);
    }
    s[i] = v;
  }
  #pragma unroll
  for (int i = 0; i < 4; i++) {
    #pragma unroll
    for (int d = 8; d; d >>= 1) s[i] += __shfl_down(s[i], d, 16);
  }
  if (cg == 0) {
    #pragma unroll
    for (int i = 0; i < 4; i++) {
      int tt = 4 * tg + i;
      if (tt < ntok) atomicAdd(&sumexp[tok_s[tt]], s[i]);
    }
  }
}

__global__ __launch_bounds__(256) void final_kernel_fb(
    const float* __restrict__ neg_cll, const float* __restrict__ z_tgt,
    const float* __restrict__ sumexp, float* __restrict__ out) {
  int i = blockIdx.x * 256 + threadIdx.x;
  if (i < NT) out[i] = neg_cll[i] + logf(sumexp[i]) - z_tgt[i];
}

// ===========================================================================
extern "C" void kernel_launch(void* const* d_in, const int* in_sizes, int n_in,
                              void* d_out, int out_size, void* d_ws,
                              size_t ws_size, hipStream_t stream) {
  const float* x      = (const float*)d_in[0];
  const int*   y      = (const int*)d_in[1];
  const float* Wc     = (const float*)d_in[2];
  const float* logits = (const float*)d_in[3];
  float* out = (float*)d_out;

  char* ws = (char*)d_ws;
  int*   offsets = (int*)ws;                      // @0, 16 B
  int*   perm    = (int*)(ws + 256);              // 16 KB
  float* sumexp  = (float*)(ws + 16896);          // 16 KB (perm-order for MFMA path)
  float* neg_cll = (float*)(ws + 33280);          // 16 KB
  float* z_tgt   = (float*)(ws + 49664);          // 16 KB
  ushort_t* xb   = (ushort_t*)(ws + 66048);       // 4224*1024*2 = 8650752 B
  ushort_t* lt   = (ushort_t*)(ws + 66048 + (size_t)NPAD_TOK * H * 2);
  const size_t WS_NEED = 66048 + (size_t)NPAD_TOK * H * 2 + (size_t)NPAD_COL * H * 2;

  setup_kernel<<<1, 1024, 0, stream>>>(y, offsets, perm, sumexp);

  if (ws_size >= WS_NEED) {
    gather_kernel<<<NPAD_TOK, 256, 0, stream>>>(x, perm, xb);
    dim3 tg((NPAD_COL + 63) / 64, H / 64);
    transpose_kernel<<<tg, 256, 0, stream>>>(logits, lt);
    head_kernel<<<NT / 4, 256, 0, stream>>>(x, y, Wc, lt, neg_cll, z_tgt);
    dim3 grid(CT_TOTAL, MAX_TTILES);
    mfma_kernel<<<grid, 256, 0, stream>>>(xb, lt, offsets, sumexp);
    final_kernel<<<NT / 256, 256, 0, stream>>>(perm, neg_cll, z_tgt, sumexp, out);
  } else {
    head_kernel_fb<<<NT / 4, 256, 0, stream>>>(x, y, Wc, logits, neg_cll, z_tgt);
    dim3 grid(FB_TOTAL, 64);
    main_kernel_fb<<<grid, 256, 0, stream>>>(x, logits, offsets, perm, sumexp);
    final_kernel_fb<<<NT / 256, 256, 0, stream>>>(neg_cll, z_tgt, sumexp, out);
  }
}